// Round 1
// baseline (1216.343 us; speedup 1.0000x reference)
//
#include <hip/hip_runtime.h>
#include <stdint.h>

#define NNODES 50000
#define NEDGES 800000
#define DDIM   128

// ---- MFMA fragment types (per guide: short8 = 8 bf16 in 4 VGPRs) ----
typedef short  short8   __attribute__((ext_vector_type(8)));
typedef float  float4v  __attribute__((ext_vector_type(4)));
typedef unsigned short ushort4v __attribute__((ext_vector_type(4)));

__device__ __forceinline__ unsigned short f2bf(float f) {
    unsigned int u = __float_as_uint(f);
    u += 0x7FFFu + ((u >> 16) & 1u);   // round-to-nearest-even
    return (unsigned short)(u >> 16);
}
__device__ __forceinline__ float silu_f(float x) { return x / (1.0f + __expf(-x)); }

// ---------------------------------------------------------------------
// prep: convert weights to bf16, transposed to n-major [n][k] so MFMA
// B-fragments (lane = n, 8 consecutive k) are contiguous 16B loads.
// We1T: [128][288] (k zero-padded 259->288); We2T/Wh2T: [128][128];
// Wh1T: [128][256]. Total 102400 elements.
// ---------------------------------------------------------------------
__global__ void prep_kernel(const float* __restrict__ We1, const float* __restrict__ We2,
                            const float* __restrict__ Wh1, const float* __restrict__ Wh2,
                            unsigned short* __restrict__ We1T, unsigned short* __restrict__ We2T,
                            unsigned short* __restrict__ Wh1T, unsigned short* __restrict__ Wh2T) {
    int i = blockIdx.x * 256 + threadIdx.x;
    if (i < 36864) {                         // We1T [128][288]
        int n = i / 288, k = i % 288;
        We1T[i] = (k < 259) ? f2bf(We1[k * 128 + n]) : (unsigned short)0;
    } else if (i < 53248) {                  // We2T [128][128]
        int j = i - 36864; int n = j >> 7, k = j & 127;
        We2T[j] = f2bf(We2[k * 128 + n]);
    } else if (i < 86016) {                  // Wh1T [128][256]
        int j = i - 53248; int n = j >> 8, k = j & 255;
        Wh1T[j] = f2bf(Wh1[k * 128 + n]);
    } else if (i < 102400) {                 // Wh2T [128][128]
        int j = i - 86016; int n = j >> 7, k = j & 127;
        Wh2T[j] = f2bf(Wh2[k * 128 + n]);
    }
}

// ---------------------------------------------------------------------
// Edge kernel: 64 edges/block, 4 waves; wave w owns edges 16w..16w+15.
// LDS edge_in [64][296] bf16 (stride 296: row=592B=16B-aligned, 2-way
// bank aliasing only). Layer1 K=288 (9 chunks), h written back into the
// same LDS rows (wave-private), layer2 K=128 (4 chunks).
// ---------------------------------------------------------------------
#define K1P  288
#define ESTR 296

__global__ __launch_bounds__(256) void edge_kernel(
    const float* __restrict__ X, const float* __restrict__ embN,
    const float* __restrict__ embE, const int* __restrict__ eidx,
    const float* __restrict__ be1, const float* __restrict__ be2,
    const unsigned short* __restrict__ We1T, const unsigned short* __restrict__ We2T,
    float* __restrict__ mij_out, float* mi) {

    __shared__ unsigned short sIn[64 * ESTR];
    __shared__ int sSrc[64], sDst[64];
    const int tid = threadIdx.x;
    const int e0  = blockIdx.x * 64;

    if (tid < 64) { sSrc[tid] = eidx[e0 + tid]; sDst[tid] = eidx[NEDGES + e0 + tid]; }
    __syncthreads();

    // gather X[src] -> cols 0..127, X[dst] -> cols 128..255 (bf16)
    for (int idx = tid; idx < 64 * 32; idx += 256) {
        int m = idx >> 5, s = idx & 31;
        const float4v xs = *(const float4v*)(X + (size_t)sSrc[m] * DDIM + s * 4);
        const float4v xd = *(const float4v*)(X + (size_t)sDst[m] * DDIM + s * 4);
        ushort4v a, b;
        a.x = f2bf(xs.x); a.y = f2bf(xs.y); a.z = f2bf(xs.z); a.w = f2bf(xs.w);
        b.x = f2bf(xd.x); b.y = f2bf(xd.y); b.z = f2bf(xd.z); b.w = f2bf(xd.w);
        *(ushort4v*)(sIn + m * ESTR + s * 4)       = a;
        *(ushort4v*)(sIn + m * ESTR + 128 + s * 4) = b;
    }
    // dist + emb_edges + zero col 259
    if (tid < 64) {
        int m = tid, e = e0 + m;
        int s = sSrc[m], d = sDst[m];
        float dx = embN[d * 3 + 0] - embN[s * 3 + 0];
        float dy = embN[d * 3 + 1] - embN[s * 3 + 1];
        float dz = embN[d * 3 + 2] - embN[s * 3 + 2];
        float dist = sqrtf(dx * dx + dy * dy + dz * dz);
        sIn[m * ESTR + 256] = f2bf(dist);
        sIn[m * ESTR + 257] = f2bf(embE[(size_t)e * 2 + 0]);
        sIn[m * ESTR + 258] = f2bf(embE[(size_t)e * 2 + 1]);
        sIn[m * ESTR + 259] = 0;
    }
    // zero cols 260..295
    for (int idx = tid; idx < 64 * 9; idx += 256) {
        int m = idx / 9, q = idx % 9;
        ushort4v z; z.x = 0; z.y = 0; z.z = 0; z.w = 0;
        *(ushort4v*)(sIn + m * ESTR + 260 + q * 4) = z;
    }
    __syncthreads();

    const int w = tid >> 6, l = tid & 63, ln = l & 15, qd = l >> 4;
    const unsigned short* aBase = sIn + (16 * w + ln) * ESTR + qd * 8;

    // ---- layer 1: [16 x 288] @ [288 x 128] ----
    float4v acc[8] = {};
#pragma unroll
    for (int kc = 0; kc < 9; ++kc) {
        short8 a = *(const short8*)(aBase + kc * 32);
#pragma unroll
        for (int nb = 0; nb < 8; ++nb) {
            short8 b = *(const short8*)(We1T + (size_t)(nb * 16 + ln) * K1P + kc * 32 + qd * 8);
            acc[nb] = __builtin_amdgcn_mfma_f32_16x16x32_bf16(a, b, acc[nb], 0, 0, 0);
        }
    }
    // epilogue 1: bias + SiLU, h -> LDS (C layout -> A layout round-trip)
    unsigned short* hBase = sIn + (16 * w) * ESTR;
#pragma unroll
    for (int nb = 0; nb < 8; ++nb) {
        int col = nb * 16 + ln;
        float bias = be1[col];
#pragma unroll
        for (int r = 0; r < 4; ++r) {
            float v = silu_f(acc[nb][r] + bias);
            hBase[(qd * 4 + r) * ESTR + col] = f2bf(v);
        }
    }
    __syncthreads();

    // ---- layer 2: [16 x 128] @ [128 x 128] ----
    float4v acc2[8] = {};
#pragma unroll
    for (int kc = 0; kc < 4; ++kc) {
        short8 a = *(const short8*)(aBase + kc * 32);
#pragma unroll
        for (int nb = 0; nb < 8; ++nb) {
            short8 b = *(const short8*)(We2T + (size_t)(nb * 16 + ln) * 128 + kc * 32 + qd * 8);
            acc2[nb] = __builtin_amdgcn_mfma_f32_16x16x32_bf16(a, b, acc2[nb], 0, 0, 0);
        }
    }
    // epilogue 2: bias + SiLU -> mij store + scatter-add into mi
#pragma unroll
    for (int nb = 0; nb < 8; ++nb) {
        int col = nb * 16 + ln;
        float bias = be2[col];
#pragma unroll
        for (int r = 0; r < 4; ++r) {
            int m = 16 * w + qd * 4 + r;
            int e = e0 + m;
            float v = silu_f(acc2[nb][r] + bias);
            mij_out[(size_t)e * DDIM + col] = v;
            atomicAdd(mi + (size_t)sDst[m] * DDIM + col, v);
        }
    }
}

// ---------------------------------------------------------------------
// Node kernel: 64 nodes/block. node_in = [X | mi] (mi read from the
// X_out region of d_out, which edge_kernel accumulated into). K=256.
// ---------------------------------------------------------------------
#define NSTR 264

__global__ __launch_bounds__(256) void node_kernel(
    const float* __restrict__ X, const float* __restrict__ bh1, const float* __restrict__ bh2,
    const unsigned short* __restrict__ Wh1T, const unsigned short* __restrict__ Wh2T,
    float* xout /* rows also hold mi on entry */) {

    __shared__ unsigned short sIn[64 * NSTR];
    const int tid = threadIdx.x;
    const int n0  = blockIdx.x * 64;

    for (int idx = tid; idx < 64 * 32; idx += 256) {
        int m = idx >> 5, s = idx & 31;
        int i = n0 + m; if (i > NNODES - 1) i = NNODES - 1;   // clamp tail rows
        const float4v xs = *(const float4v*)(X    + (size_t)i * DDIM + s * 4);
        const float4v ms = *(const float4v*)(xout + (size_t)i * DDIM + s * 4);
        ushort4v a, b;
        a.x = f2bf(xs.x); a.y = f2bf(xs.y); a.z = f2bf(xs.z); a.w = f2bf(xs.w);
        b.x = f2bf(ms.x); b.y = f2bf(ms.y); b.z = f2bf(ms.z); b.w = f2bf(ms.w);
        *(ushort4v*)(sIn + m * NSTR + s * 4)       = a;
        *(ushort4v*)(sIn + m * NSTR + 128 + s * 4) = b;
    }
    __syncthreads();

    const int w = tid >> 6, l = tid & 63, ln = l & 15, qd = l >> 4;
    const unsigned short* aBase = sIn + (16 * w + ln) * NSTR + qd * 8;

    // layer 1: K=256
    float4v acc[8] = {};
#pragma unroll
    for (int kc = 0; kc < 8; ++kc) {
        short8 a = *(const short8*)(aBase + kc * 32);
#pragma unroll
        for (int nb = 0; nb < 8; ++nb) {
            short8 b = *(const short8*)(Wh1T + (size_t)(nb * 16 + ln) * 256 + kc * 32 + qd * 8);
            acc[nb] = __builtin_amdgcn_mfma_f32_16x16x32_bf16(a, b, acc[nb], 0, 0, 0);
        }
    }
    unsigned short* hBase = sIn + (16 * w) * NSTR;
#pragma unroll
    for (int nb = 0; nb < 8; ++nb) {
        int col = nb * 16 + ln;
        float bias = bh1[col];
#pragma unroll
        for (int r = 0; r < 4; ++r) {
            float v = silu_f(acc[nb][r] + bias);
            hBase[(qd * 4 + r) * NSTR + col] = f2bf(v);
        }
    }
    __syncthreads();

    // layer 2: K=128, NO final activation
    float4v acc2[8] = {};
#pragma unroll
    for (int kc = 0; kc < 4; ++kc) {
        short8 a = *(const short8*)(aBase + kc * 32);
#pragma unroll
        for (int nb = 0; nb < 8; ++nb) {
            short8 b = *(const short8*)(Wh2T + (size_t)(nb * 16 + ln) * 128 + kc * 32 + qd * 8);
            acc2[nb] = __builtin_amdgcn_mfma_f32_16x16x32_bf16(a, b, acc2[nb], 0, 0, 0);
        }
    }
#pragma unroll
    for (int nb = 0; nb < 8; ++nb) {
        int col = nb * 16 + ln;
        float bias = bh2[col];
#pragma unroll
        for (int r = 0; r < 4; ++r) {
            int i = n0 + 16 * w + qd * 4 + r;
            float v = acc2[nb][r] + bias;
            if (i < NNODES) xout[(size_t)i * DDIM + col] = v;
        }
    }
}

// ---------------------------------------------------------------------
extern "C" void kernel_launch(void* const* d_in, const int* in_sizes, int n_in,
                              void* d_out, int out_size, void* d_ws, size_t ws_size,
                              hipStream_t stream) {
    const float* X    = (const float*)d_in[0];
    // d_in[1] = E (unused by the reference computation)
    const float* embN = (const float*)d_in[2];
    const float* embE = (const float*)d_in[3];
    const int*   eidx = (const int*)d_in[4];
    const float* We1  = (const float*)d_in[5];
    const float* be1  = (const float*)d_in[6];
    const float* We2  = (const float*)d_in[7];
    const float* be2  = (const float*)d_in[8];
    const float* Wh1  = (const float*)d_in[9];
    const float* bh1  = (const float*)d_in[10];
    const float* Wh2  = (const float*)d_in[11];
    const float* bh2  = (const float*)d_in[12];

    float* out   = (float*)d_out;
    float* xout  = out;               // X_out region doubles as mi accumulator
    float* mij   = out + 6400000;     // 800000 x 128
    float* oEmbN = out + 108800000;   // 50000 x 3
    float* oEmbE = out + 108950000;   // 800000 x 2

    unsigned short* We1T = (unsigned short*)d_ws;   // [128][288]
    unsigned short* We2T = We1T + 36864;            // [128][128]
    unsigned short* Wh1T = We1T + 53248;            // [128][256]
    unsigned short* Wh2T = We1T + 86016;            // [128][128]

    hipMemsetAsync(xout, 0, (size_t)6400000 * sizeof(float), stream);   // zero mi
    prep_kernel<<<400, 256, 0, stream>>>(We1, We2, Wh1, Wh2, We1T, We2T, Wh1T, Wh2T);
    edge_kernel<<<NEDGES / 64, 256, 0, stream>>>(X, embN, embE, eidx, be1, be2,
                                                 We1T, We2T, mij, xout);
    node_kernel<<<(NNODES + 63) / 64, 256, 0, stream>>>(X, bh1, bh2, Wh1T, Wh2T, xout);
    hipMemcpyAsync(oEmbN, (void*)embN, (size_t)150000 * sizeof(float),
                   hipMemcpyDeviceToDevice, stream);
    hipMemcpyAsync(oEmbE, (void*)embE, (size_t)1600000 * sizeof(float),
                   hipMemcpyDeviceToDevice, stream);
}